// Round 1
// 304.320 us; speedup vs baseline: 1.6966x; 1.6966x over previous
//
#include <hip/hip_runtime.h>
#include <math.h>

#define TOKENS 16384
#define DMODEL 2048
#define NEXP   256
#define TOPK   8
#define BM     32
#define BK     32
#define NT     (DMODEL / BK)   // 64 k-tiles

typedef _Float16 f16;
typedef _Float16 f16x8 __attribute__((ext_vector_type(8)));
typedef _Float16 f16x4 __attribute__((ext_vector_type(4)));
typedef float    f32x4 __attribute__((ext_vector_type(4)));

// barrier that does NOT drain vmcnt (keeps B/x prefetch in flight)
#define BAR() asm volatile("s_waitcnt lgkmcnt(0)\ns_barrier" ::: "memory")

// ---------------- prep: w (E x D f32) -> fp16 split planes, tile-major ----------------
// plane layout: idx = t*(NEXP*BK) + e*BK + ki   (t = d>>5, ki = d&31)
// hw = f16(64*w), lw = f16((64*w - hw) * 2048)
__global__ void k_prep(const float* __restrict__ w,
                       f16* __restrict__ wsH, f16* __restrict__ wsL) {
    int g  = blockIdx.x * 256 + threadIdx.x;
    int ki = g & 31;
    int e  = (g >> 5) & 255;
    int t  = g >> 13;
    float v = w[(size_t)e * DMODEL + t * 32 + ki] * 64.0f;
    f16 h = (f16)v;
    f16 l = (f16)((v - (float)h) * 2048.0f);
    wsH[g] = h;
    wsL[g] = l;
}

// ---------------- zero the counts region of d_out ----------------
__global__ void k_zero(float* __restrict__ counts) {
    counts[threadIdx.x] = 0.0f;
}

// ---------------- main: split-fp16 MFMA GEMM + bias + top-8 + softmax + histogram ----------------
__global__ __launch_bounds__(256, 2) void k_main(
        const float* __restrict__ x,
        const f16*   __restrict__ wh,
        const f16*   __restrict__ wl,
        const float* __restrict__ bias,
        float* __restrict__ out) {
    __shared__ float logits[BM][NEXP];      // 32 KB
    __shared__ f16   AH[2][BM * BK];        // 4 KB (double-buffered hi plane)
    __shared__ f16   AL[2][BM * BK];        // 4 KB (lo plane)
    __shared__ float hist[NEXP];            // 1 KB

    const int tid  = threadIdx.x;
    const int tok0 = blockIdx.x * BM;
    const int lane = tid & 63;
    const int wv   = tid >> 6;              // 0..3
    const int eb   = lane & 15;
    const int kq   = lane >> 4;             // 0..3 (k-octet)

    hist[tid] = 0.0f;

    // ---- x staging map: thread -> (tok = tid>>3, 4 consecutive k) ----
    const int s_tok = tid >> 3;
    const int s_k4  = (tid & 7) * 4;
    const float* xp = x + (size_t)(tok0 + s_tok) * DMODEL + s_k4;
    // XOR-swizzled LDS write offset (halfs): chunk' = chunk ^ ((tok>>1)&3)
    const int a_woff = s_tok * 32 + (((s_k4 >> 3) ^ ((s_tok >> 1) & 3)) * 8) + (s_k4 & 7);

    // ---- A fragment read offsets (halfs), same swizzle ----
    const int tk0 = eb;
    const int tk1 = 16 + eb;
    const int ro0 = tk0 * 32 + ((kq ^ ((tk0 >> 1) & 3)) * 8);
    const int ro1 = tk1 * 32 + ((kq ^ ((tk1 >> 1) & 3)) * 8);

    // ---- B fragment global offsets (halfs): wave owns n-frags wv*4..wv*4+3 ----
    size_t bo[4];
#pragma unroll
    for (int q = 0; q < 4; q++)
        bo[q] = (size_t)(((wv * 4 + q) * 16 + eb) * 32 + kq * 8);

    f32x4 acc0[2][4], acc1[2][4];
#pragma unroll
    for (int m = 0; m < 2; m++)
#pragma unroll
        for (int q = 0; q < 4; q++) {
            acc0[m][q] = (f32x4){0.0f, 0.0f, 0.0f, 0.0f};
            acc1[m][q] = (f32x4){0.0f, 0.0f, 0.0f, 0.0f};
        }

    // ---- prologue: stage A(0), load B(0), prefetch x(1) ----
    float4 xrA = *(const float4*)xp;   // x tile 0
    f16x8 bh[4], bl[4];
#pragma unroll
    for (int q = 0; q < 4; q++) {
        bh[q] = *(const f16x8*)(wh + bo[q]);
        bl[q] = *(const f16x8*)(wl + bo[q]);
    }
    {
        f16 h0 = (f16)xrA.x, h1 = (f16)xrA.y, h2 = (f16)xrA.z, h3 = (f16)xrA.w;
        f16x4 hv = {h0, h1, h2, h3};
        f16x4 lv = {(f16)((xrA.x - (float)h0) * 2048.0f),
                    (f16)((xrA.y - (float)h1) * 2048.0f),
                    (f16)((xrA.z - (float)h2) * 2048.0f),
                    (f16)((xrA.w - (float)h3) * 2048.0f)};
        *(f16x4*)&AH[0][a_woff] = hv;
        *(f16x4*)&AL[0][a_woff] = lv;
    }
    xrA = *(const float4*)(xp + BK);   // x tile 1
    BAR();

    // ---- main k-loop: one barrier per tile; B + x prefetch stay in flight ----
    for (int t = 0; t < NT; ++t) {
        const int notlast = (t + 1 < NT);
        f16x8 nbh[4], nbl[4];
        float4 xrB = xrA;
        if (notlast) {
            const size_t tb = (size_t)(t + 1) * (NEXP * BK);
#pragma unroll
            for (int q = 0; q < 4; q++) {
                nbh[q] = *(const f16x8*)(wh + tb + bo[q]);
                nbl[q] = *(const f16x8*)(wl + tb + bo[q]);
            }
            if (t + 2 < NT) xrB = *(const float4*)(xp + (size_t)(t + 2) * BK);
        }

        const f16* aH = AH[t & 1];
        const f16* aL = AL[t & 1];
        f16x8 a0h = *(const f16x8*)(aH + ro0);
        f16x8 a1h = *(const f16x8*)(aH + ro1);
        f16x8 a0l = *(const f16x8*)(aL + ro0);
        f16x8 a1l = *(const f16x8*)(aL + ro1);

#pragma unroll
        for (int q = 0; q < 4; q++) {
            acc0[0][q] = __builtin_amdgcn_mfma_f32_16x16x32_f16(a0h, bh[q], acc0[0][q], 0, 0, 0);
            acc0[1][q] = __builtin_amdgcn_mfma_f32_16x16x32_f16(a1h, bh[q], acc0[1][q], 0, 0, 0);
        }
#pragma unroll
        for (int q = 0; q < 4; q++) {
            acc1[0][q] = __builtin_amdgcn_mfma_f32_16x16x32_f16(a0l, bh[q], acc1[0][q], 0, 0, 0);
            acc1[1][q] = __builtin_amdgcn_mfma_f32_16x16x32_f16(a1l, bh[q], acc1[1][q], 0, 0, 0);
        }
#pragma unroll
        for (int q = 0; q < 4; q++) {
            acc1[0][q] = __builtin_amdgcn_mfma_f32_16x16x32_f16(a0h, bl[q], acc1[0][q], 0, 0, 0);
            acc1[1][q] = __builtin_amdgcn_mfma_f32_16x16x32_f16(a1h, bl[q], acc1[1][q], 0, 0, 0);
        }

        if (notlast) {
            // stage A(t+1) into the other buffer (consumes xrA = x(t+1))
            f16 h0 = (f16)xrA.x, h1 = (f16)xrA.y, h2 = (f16)xrA.z, h3 = (f16)xrA.w;
            f16x4 hv = {h0, h1, h2, h3};
            f16x4 lv = {(f16)((xrA.x - (float)h0) * 2048.0f),
                        (f16)((xrA.y - (float)h1) * 2048.0f),
                        (f16)((xrA.z - (float)h2) * 2048.0f),
                        (f16)((xrA.w - (float)h3) * 2048.0f)};
            *(f16x4*)&AH[(t + 1) & 1][a_woff] = hv;
            *(f16x4*)&AL[(t + 1) & 1][a_woff] = lv;
            xrA = xrB;
            BAR();
#pragma unroll
            for (int q = 0; q < 4; q++) { bh[q] = nbh[q]; bl[q] = nbl[q]; }
        }
    }

    // ---- epilogue: descale + bias, write logits to LDS (C layout: col=lane&15, row=(lane>>4)*4+i) ----
#pragma unroll
    for (int m = 0; m < 2; m++) {
#pragma unroll
        for (int q = 0; q < 4; q++) {
            const int e = (wv * 4 + q) * 16 + eb;
            const float b = bias[e];
#pragma unroll
            for (int i = 0; i < 4; i++) {
                const int tk = m * 16 + kq * 4 + i;
                logits[tk][e] = (acc0[m][q][i] + acc1[m][q][i] * (1.0f / 2048.0f)) * (1.0f / 64.0f) + b;
            }
        }
    }
    __syncthreads();

    // ---- top-8 per token; each wave handles 8 tokens (verbatim from passing kernel) ----
    for (int tt = 0; tt < 8; tt++) {
        const int tok = wv * 8 + tt;
        float4 v4 = *(const float4*)&logits[tok][lane * 4];
        float lv[4] = {v4.x, v4.y, v4.z, v4.w};
        int msk = 0xF;
        float topv[TOPK];
        int   topi[TOPK];
#pragma unroll
        for (int r = 0; r < TOPK; r++) {
            float bvv = -INFINITY;
            int   bii = 0x7fffffff;
#pragma unroll
            for (int j = 0; j < 4; j++) {
                if (msk & (1 << j)) {
                    float vv = lv[j];
                    int   ii = lane * 4 + j;
                    if (vv > bvv || (vv == bvv && ii < bii)) { bvv = vv; bii = ii; }
                }
            }
#pragma unroll
            for (int off = 32; off > 0; off >>= 1) {
                float ov = __shfl_xor(bvv, off);
                int   oi = __shfl_xor(bii, off);
                if (ov > bvv || (ov == bvv && oi < bii)) { bvv = ov; bii = oi; }
            }
            topv[r] = bvv;
            topi[r] = bii;
            if ((bii >> 2) == lane) msk &= ~(1 << (bii & 3));
        }
        float m = topv[0];
        float s = 0.0f;
#pragma unroll
        for (int r = 0; r < TOPK; r++) s += expf(topv[r] - m);

        const int gtok = tok0 + tok;
        if (lane < TOPK) {
            out[(size_t)gtok * TOPK + lane] = expf(topv[lane] - m) / s;
        } else if (lane < 2 * TOPK) {
            int r = lane - TOPK;
            out[(size_t)TOKENS * TOPK + (size_t)gtok * TOPK + r] = (float)topi[r];
            atomicAdd(&hist[topi[r]], 1.0f);
        }
    }
    __syncthreads();
    float hv = hist[tid];
    if (hv != 0.0f) atomicAdd(&out[(size_t)2 * TOKENS * TOPK + tid], hv);
}

// ---------------- fallback (no workspace): previous passing fp32 VALU kernel ----------------
__global__ __launch_bounds__(256, 3) void k_main_fb(
        const float* __restrict__ x,
        const float* __restrict__ wsrc,       // w (ExD)
        const float* __restrict__ bias,
        float* __restrict__ out) {
    __shared__ float xT[16][BM];
    __shared__ float wS[16][NEXP];
    __shared__ float logits[BM][NEXP];
    __shared__ float hist[NEXP];

    const int tid  = threadIdx.x;
    const int tok0 = blockIdx.x * BM;
    const int ty   = tid >> 5;
    const int tx   = tid & 31;

    hist[tid] = 0.0f;

    float acc[4][8];
#pragma unroll
    for (int i = 0; i < 4; i++)
#pragma unroll
        for (int j = 0; j < 8; j++) acc[i][j] = 0.0f;

    const int lx_tok = tid >> 3;
    const int lx_d   = (tid & 7) * 2;

    for (int k0 = 0; k0 < DMODEL; k0 += 16) {
        __syncthreads();
        float2 xv = *(const float2*)&x[(size_t)(tok0 + lx_tok) * DMODEL + k0 + lx_d];
        xT[lx_d][lx_tok]     = xv.x;
        xT[lx_d + 1][lx_tok] = xv.y;
#pragma unroll
        for (int i = 0; i < 16; i++)
            wS[i][tid] = wsrc[(size_t)tid * DMODEL + k0 + i];
        __syncthreads();
#pragma unroll
        for (int k = 0; k < 16; k++) {
            float4 a  = *(const float4*)&xT[k][ty * 4];
            float4 b0 = *(const float4*)&wS[k][tx * 8];
            float4 b1 = *(const float4*)&wS[k][tx * 8 + 4];
            float av[4] = {a.x, a.y, a.z, a.w};
            float bv[8] = {b0.x, b0.y, b0.z, b0.w, b1.x, b1.y, b1.z, b1.w};
#pragma unroll
            for (int i = 0; i < 4; i++)
#pragma unroll
                for (int j = 0; j < 8; j++)
                    acc[i][j] = fmaf(av[i], bv[j], acc[i][j]);
        }
    }

    float bb[8];
#pragma unroll
    for (int j = 0; j < 8; j++) bb[j] = bias[tx * 8 + j];
#pragma unroll
    for (int i = 0; i < 4; i++) {
#pragma unroll
        for (int j = 0; j < 8; j++)
            logits[ty * 4 + i][tx * 8 + j] = acc[i][j] + bb[j];
    }
    __syncthreads();

    const int lane = tid & 63;
    const int wv   = tid >> 6;
    for (int tt = 0; tt < 8; tt++) {
        const int tok = wv * 8 + tt;
        float4 v4 = *(const float4*)&logits[tok][lane * 4];
        float lv[4] = {v4.x, v4.y, v4.z, v4.w};
        int msk = 0xF;
        float topv[TOPK];
        int   topi[TOPK];
#pragma unroll
        for (int r = 0; r < TOPK; r++) {
            float bvv = -INFINITY;
            int   bii = 0x7fffffff;
#pragma unroll
            for (int j = 0; j < 4; j++) {
                if (msk & (1 << j)) {
                    float vv = lv[j];
                    int   ii = lane * 4 + j;
                    if (vv > bvv || (vv == bvv && ii < bii)) { bvv = vv; bii = ii; }
                }
            }
#pragma unroll
            for (int off = 32; off > 0; off >>= 1) {
                float ov = __shfl_xor(bvv, off);
                int   oi = __shfl_xor(bii, off);
                if (ov > bvv || (ov == bvv && oi < bii)) { bvv = ov; bii = oi; }
            }
            topv[r] = bvv;
            topi[r] = bii;
            if ((bii >> 2) == lane) msk &= ~(1 << (bii & 3));
        }
        float m = topv[0];
        float s = 0.0f;
#pragma unroll
        for (int r = 0; r < TOPK; r++) s += expf(topv[r] - m);

        const int gtok = tok0 + tok;
        if (lane < TOPK) {
            out[(size_t)gtok * TOPK + lane] = expf(topv[lane] - m) / s;
        } else if (lane < 2 * TOPK) {
            int r = lane - TOPK;
            out[(size_t)TOKENS * TOPK + (size_t)gtok * TOPK + r] = (float)topi[r];
            atomicAdd(&hist[topi[r]], 1.0f);
        }
    }
    __syncthreads();
    float hv = hist[tid];
    if (hv != 0.0f) atomicAdd(&out[(size_t)2 * TOKENS * TOPK + tid], hv);
}

// ---------------- stats: std(ddof=1)/mean, max, min, expected ----------------
__global__ void k_stats(float* __restrict__ out) {
    __shared__ float sm[NEXP];
    const float* counts = out + (size_t)2 * TOKENS * TOPK;
    const int t = threadIdx.x;
    float c = counts[t];

    sm[t] = c;
    __syncthreads();
    for (int s = 128; s > 0; s >>= 1) {
        if (t < s) sm[t] += sm[t + s];
        __syncthreads();
    }
    float mean = sm[0] / (float)NEXP;
    __syncthreads();

    float d = c - mean;
    sm[t] = d * d;
    __syncthreads();
    for (int s = 128; s > 0; s >>= 1) {
        if (t < s) sm[t] += sm[t + s];
        __syncthreads();
    }
    float var = sm[0] / (float)(NEXP - 1);
    __syncthreads();

    sm[t] = c;
    __syncthreads();
    for (int s = 128; s > 0; s >>= 1) {
        if (t < s) sm[t] = fmaxf(sm[t], sm[t + s]);
        __syncthreads();
    }
    float mx = sm[0];
    __syncthreads();

    sm[t] = c;
    __syncthreads();
    for (int s = 128; s > 0; s >>= 1) {
        if (t < s) sm[t] = fminf(sm[t], sm[t + s]);
        __syncthreads();
    }
    float mn = sm[0];

    if (t == 0) {
        float* scal = out + (size_t)2 * TOKENS * TOPK + NEXP;
        scal[0] = sqrtf(var) / (mean + 1e-6f);
        scal[1] = mx;
        scal[2] = mn;
        scal[3] = (float)(TOKENS * TOPK) / (float)NEXP;
    }
}

extern "C" void kernel_launch(void* const* d_in, const int* in_sizes, int n_in,
                              void* d_out, int out_size, void* d_ws, size_t ws_size,
                              hipStream_t stream) {
    const float* x    = (const float*)d_in[0];
    const float* w    = (const float*)d_in[1];
    const float* bias = (const float*)d_in[2];
    float* out = (float*)d_out;

    const size_t need = (size_t)DMODEL * NEXP * 2 * sizeof(_Float16);  // 2 MB
    if (ws_size >= need) {
        f16* wsH = (f16*)d_ws;
        f16* wsL = wsH + (size_t)DMODEL * NEXP;
        k_prep<<<(DMODEL * NEXP) / 256, 256, 0, stream>>>(w, wsH, wsL);
        k_zero<<<1, NEXP, 0, stream>>>(out + (size_t)2 * TOKENS * TOPK);
        k_main<<<TOKENS / BM, 256, 0, stream>>>(x, wsH, wsL, bias, out);
    } else {
        k_zero<<<1, NEXP, 0, stream>>>(out + (size_t)2 * TOKENS * TOPK);
        k_main_fb<<<TOKENS / BM, 256, 0, stream>>>(x, w, bias, out);
    }
    k_stats<<<1, NEXP, 0, stream>>>(out);
}